// Round 1
// baseline (1623.631 us; speedup 1.0000x reference)
//
#include <hip/hip_runtime.h>
#include <cstddef>

#define B_   64
#define L_   512
#define C_   321
#define P_   96
#define N_   2000
#define KTOT 608   // 512 x-cols + 48 seasonal-dict rows + 48 trend-dict rows
#define CT   32
#define KC   16

// ---------------------------------------------------------------------------
// Precompute 1: WX columns 0..511 of M.
//   W1s[p,l] = sum_t wfs[p,t]*wxs[t,l]   (t<96)
//   W1t[p,l] = sum_t wft[p,t]*wxt[t,l]
//   D = W1t - W1s;  WX = W1s + D*T  (T = clamped box-filter matrix, K=25)
//   off-folding:  +(1-s1s) at col 511;  +(s1s-s1t)*T[511,·] spread over cols
//   499..511 (1/25 each, 13/25 at col 511), where s1* = row sums of W1*.
// One block per p.
// ---------------------------------------------------------------------------
__global__ __launch_bounds__(256) void k_build_wx(
    const float* __restrict__ wfs, const float* __restrict__ wxs,
    const float* __restrict__ wft, const float* __restrict__ wxt,
    float* __restrict__ M)
{
    int p = blockIdx.x;
    int tid = threadIdx.x;
    __shared__ float As[L_], At[L_];
    __shared__ float fs[P_], ft[P_];
    __shared__ float rs[4], rt[4];
    if (tid < P_) { fs[tid] = wfs[p*2*P_ + tid]; ft[tid] = wft[p*2*P_ + tid]; }
    __syncthreads();
    float ps = 0.f, pt = 0.f;
    for (int l = tid; l < L_; l += 256) {
        float as = 0.f, at = 0.f;
        #pragma unroll 8
        for (int t = 0; t < P_; ++t) {
            as += fs[t] * wxs[t*L_ + l];
            at += ft[t] * wxt[t*L_ + l];
        }
        As[l] = as; At[l] = at;
        ps += as; pt += at;
    }
    for (int o = 32; o > 0; o >>= 1) {
        ps += __shfl_down(ps, o);
        pt += __shfl_down(pt, o);
    }
    int wid = tid >> 6, lid = tid & 63;
    if (lid == 0) { rs[wid] = ps; rt[wid] = pt; }
    __syncthreads();
    float s1s = rs[0] + rs[1] + rs[2] + rs[3];
    float s1t = rt[0] + rt[1] + rt[2] + rt[3];
    for (int m = tid; m < L_; m += 256) {
        float box = 0.f;
        if (m == 0) {
            for (int l = 0; l <= 12; ++l) box += (float)(13 - l) * (At[l] - As[l]);
        } else if (m == L_ - 1) {
            for (int l = L_ - 13; l <= L_ - 1; ++l) box += (float)(l - (L_ - 13) + 1) * (At[l] - As[l]);
        } else {
            int lo = m - 12 < 0 ? 0 : m - 12;
            int hi = m + 12 > L_ - 1 ? L_ - 1 : m + 12;
            for (int l = lo; l <= hi; ++l) box += At[l] - As[l];
        }
        float v = As[m] + box * (1.0f / 25.0f);
        if (m >= L_ - 13 && m <= L_ - 2) v += (s1s - s1t) * (1.0f / 25.0f);
        if (m == L_ - 1) v += (1.0f - s1s) + (s1s - s1t) * (13.0f / 25.0f);
        M[p*KTOT + m] = v;
    }
}

// ---------------------------------------------------------------------------
// Precompute 2: WR columns 512..607 of M, plus BETA.
//   col 512+j     (j<48):  sum_t wfs[p,96+t]*rws_i[t,q]   (j -> (i,q))
//   col 512+48+j  (j<48):  same with wft/rwt_i
//   BETA[p] = bfs+bft + wf[:, :96]·bx + wf[:, 96:]·(sum_i rb_i)   (both branches)
// One block per p, 128 threads.
// ---------------------------------------------------------------------------
__global__ __launch_bounds__(128) void k_build_wr(
    const float* __restrict__ wfs, const float* __restrict__ wft,
    const float* __restrict__ rws0, const float* __restrict__ rwt0,
    const float* __restrict__ rws1, const float* __restrict__ rwt1,
    const float* __restrict__ rws2, const float* __restrict__ rwt2,
    const float* __restrict__ rws3, const float* __restrict__ rwt3,
    const float* __restrict__ bxs, const float* __restrict__ bxt,
    const float* __restrict__ rbs0, const float* __restrict__ rbs1,
    const float* __restrict__ rbs2, const float* __restrict__ rbs3,
    const float* __restrict__ rbt0, const float* __restrict__ rbt1,
    const float* __restrict__ rbt2, const float* __restrict__ rbt3,
    const float* __restrict__ bfs, const float* __restrict__ bft,
    float* __restrict__ M, float* __restrict__ beta)
{
    int p = blockIdx.x;
    int j = threadIdx.x;
    if (j < 96) {
        bool sea = j < 48;
        int jj = sea ? j : j - 48;
        const float* wf = sea ? wfs : wft;
        const float* rw; int len, q;
        if (jj < 24)      { q = jj;      len = 24; rw = sea ? rws0 : rwt0; }
        else if (jj < 36) { q = jj - 24; len = 12; rw = sea ? rws1 : rwt1; }
        else if (jj < 44) { q = jj - 36; len = 8;  rw = sea ? rws2 : rwt2; }
        else              { q = jj - 44; len = 4;  rw = sea ? rws3 : rwt3; }
        float a = 0.f;
        for (int t = 0; t < P_; ++t) a += wf[p*2*P_ + P_ + t] * rw[t*len + q];
        M[p*KTOT + L_ + j] = a;
    } else if (j == 96) {
        float s = bfs[p] + bft[p];
        for (int t = 0; t < P_; ++t) {
            s += wfs[p*2*P_ + t] * bxs[t] + wft[p*2*P_ + t] * bxt[t];
            s += wfs[p*2*P_ + P_ + t] * (rbs0[t] + rbs1[t] + rbs2[t] + rbs3[t]);
            s += wft[p*2*P_ + P_ + t] * (rbt0[t] + rbt1[t] + rbt2[t] + rbt3[t]);
        }
        beta[p] = s;
    }
}

// ---------------------------------------------------------------------------
// Main GEMM: out[b,p,c] = BETA[p] + sum_k M[p,k] * Xcat[b,k,c]
//   Xcat rows 0..511   : x_enc[b, k, :]
//   Xcat rows 512..559 : gathered seasonal dict rows (j -> (i, q*g))
//   Xcat rows 560..607 : gathered trend dict rows
// Grid (ceil(C/32), B). Block 256 = 8 (tx, 4 cols each) x 32 (ty).
// Micro-tile 3p x 4c per thread; K staged in 16-chunks in LDS.
// ---------------------------------------------------------------------------
__global__ __launch_bounds__(256) void k_main(
    const float* __restrict__ x, const int* __restrict__ index,
    const float* __restrict__ rds, const float* __restrict__ rdt,
    const float* __restrict__ M, const float* __restrict__ beta,
    float* __restrict__ out)
{
    __shared__ float Xs[KC][CT];
    __shared__ float Ms[KC][P_];
    int b   = blockIdx.y;
    int c0  = blockIdx.x * CT;
    int tid = threadIdx.x;
    int idx = index[b];
    int tx = tid & 7;    // 4 consecutive cols each -> covers 32 cols
    int ty = tid >> 3;   // 0..31, p = ty + 32*jp
    int sc = tid & 31;   // staging column
    int sk = tid >> 5;   // staging row (2 passes)
    int cc = c0 + sc;
    bool cok = cc < C_;

    float acc[3][4];
    #pragma unroll
    for (int i = 0; i < 3; ++i)
        #pragma unroll
        for (int q = 0; q < 4; ++q) acc[i][q] = 0.f;

    for (int k0 = 0; k0 < KTOT; k0 += KC) {
        __syncthreads();
        #pragma unroll
        for (int r = 0; r < 2; ++r) {
            int k = k0 + sk + 8*r;
            const float* src;
            if (k < L_) {
                src = x + ((size_t)b*L_ + k)*C_;
            } else {
                int j = k - L_;
                const float* dict = rds;
                if (j >= 48) { j -= 48; dict = rdt; }
                int i, rr;
                if (j < 24)      { i = 0; rr = 4*j; }
                else if (j < 36) { i = 1; rr = 8*(j-24); }
                else if (j < 44) { i = 2; rr = 12*(j-36); }
                else             { i = 3; rr = 24*(j-44); }
                src = dict + (((size_t)i*N_ + idx)*P_ + rr)*C_;
            }
            Xs[sk + 8*r][sc] = cok ? src[cc] : 0.f;
        }
        for (int t = tid; t < KC*P_; t += 256) {
            int pp = t >> 4;          // p row
            int kk = t & (KC - 1);    // k within chunk
            Ms[kk][pp] = M[pp*KTOT + k0 + kk];
        }
        __syncthreads();
        #pragma unroll
        for (int kk = 0; kk < KC; ++kk) {
            float4 xq = *reinterpret_cast<const float4*>(&Xs[kk][tx*4]);
            float m0 = Ms[kk][ty];
            float m1 = Ms[kk][ty + 32];
            float m2 = Ms[kk][ty + 64];
            acc[0][0] += m0*xq.x; acc[0][1] += m0*xq.y; acc[0][2] += m0*xq.z; acc[0][3] += m0*xq.w;
            acc[1][0] += m1*xq.x; acc[1][1] += m1*xq.y; acc[1][2] += m1*xq.z; acc[1][3] += m1*xq.w;
            acc[2][0] += m2*xq.x; acc[2][1] += m2*xq.y; acc[2][2] += m2*xq.z; acc[2][3] += m2*xq.w;
        }
    }

    #pragma unroll
    for (int jp = 0; jp < 3; ++jp) {
        int p = ty + 32*jp;
        float bv = beta[p];
        size_t base = ((size_t)b*P_ + p)*C_;
        int cbase = c0 + tx*4;
        #pragma unroll
        for (int q = 0; q < 4; ++q) {
            int c = cbase + q;
            if (c < C_) out[base + c] = acc[jp][q] + bv;
        }
    }
}

extern "C" void kernel_launch(void* const* d_in, const int* in_sizes, int n_in,
                              void* d_out, int out_size, void* d_ws, size_t ws_size,
                              hipStream_t stream)
{
    (void)in_sizes; (void)n_in; (void)out_size; (void)ws_size;
    const float* x    = (const float*)d_in[0];
    const int*   idx  = (const int*)  d_in[1];
    const float* rds  = (const float*)d_in[2];
    const float* rdt  = (const float*)d_in[3];
    const float* wxs  = (const float*)d_in[4];
    const float* bxs  = (const float*)d_in[5];
    const float* wxt  = (const float*)d_in[6];
    const float* bxt  = (const float*)d_in[7];
    const float* wfs  = (const float*)d_in[8];
    const float* bfs  = (const float*)d_in[9];
    const float* wft  = (const float*)d_in[10];
    const float* bft  = (const float*)d_in[11];
    const float* rws0 = (const float*)d_in[12];
    const float* rbs0 = (const float*)d_in[13];
    const float* rwt0 = (const float*)d_in[14];
    const float* rbt0 = (const float*)d_in[15];
    const float* rws1 = (const float*)d_in[16];
    const float* rbs1 = (const float*)d_in[17];
    const float* rwt1 = (const float*)d_in[18];
    const float* rbt1 = (const float*)d_in[19];
    const float* rws2 = (const float*)d_in[20];
    const float* rbs2 = (const float*)d_in[21];
    const float* rwt2 = (const float*)d_in[22];
    const float* rbt2 = (const float*)d_in[23];
    const float* rws3 = (const float*)d_in[24];
    const float* rbs3 = (const float*)d_in[25];
    const float* rwt3 = (const float*)d_in[26];
    const float* rbt3 = (const float*)d_in[27];
    float* out = (float*)d_out;

    float* M    = (float*)d_ws;        // 96*608 floats
    float* beta = M + P_*KTOT;         // 96 floats

    hipLaunchKernelGGL(k_build_wx, dim3(P_), dim3(256), 0, stream, wfs, wxs, wft, wxt, M);
    hipLaunchKernelGGL(k_build_wr, dim3(P_), dim3(128), 0, stream,
        wfs, wft, rws0, rwt0, rws1, rwt1, rws2, rwt2, rws3, rwt3,
        bxs, bxt, rbs0, rbs1, rbs2, rbs3, rbt0, rbt1, rbt2, rbt3, bfs, bft, M, beta);
    hipLaunchKernelGGL(k_main, dim3((C_ + CT - 1)/CT, B_), dim3(256), 0, stream,
        x, idx, rds, rdt, M, beta, out);
}